// Round 11
// baseline (170.831 us; speedup 1.0000x reference)
//
#include <hip/hip_runtime.h>
#include <hip/hip_bf16.h>
#include <math.h>

typedef __bf16 bf16x8 __attribute__((ext_vector_type(8)));
typedef __bf16 bf16x4 __attribute__((ext_vector_type(4)));
typedef float f32x4 __attribute__((ext_vector_type(4)));

#define TM 128
#define BK 64   // bf16 elements per K-tile (8 chunks of 16B per row)

// Leading barrier with COUNTED vmcnt (T4): previous K-step's 8 loads/thread
// must be done (they filled buf[cur]); this step's 8 prefetch loads stay in
// flight across the barrier. NOTE: __syncthreads() would vmcnt(0)-drain the
// prefetch (this is why the round-4/5 dbuf measured exactly null).
#define LEAD_VMBAR(N) do {                                        \
    asm volatile("s_waitcnt vmcnt(" #N ")" ::: "memory");         \
    __builtin_amdgcn_sched_barrier(0);                            \
    __builtin_amdgcn_s_barrier();                                 \
    __builtin_amdgcn_sched_barrier(0);                            \
} while (0)

// Trailing barrier: all waves consumed buf[cur] (MFMA lgkm waits precede in
// program order) -> next iter may overwrite. No vmcnt drain.
#define TRAIL_BAR() do {                                          \
    __builtin_amdgcn_sched_barrier(0);                            \
    __builtin_amdgcn_s_barrier();                                 \
    __builtin_amdgcn_sched_barrier(0);                            \
} while (0)

// ---------------------------------------------------------------------------
// Head-dim permutation: q/k/v/ao store dim d at position p = 4*(d&15)+(d>>4)
// (within each 64-dim head block). Attention is dim-order-invariant, so only
// w_out's input-dim columns must be permuted to match (done in split_mat).
// ---------------------------------------------------------------------------

__device__ inline void async16(const void* g, void* l) {
    __builtin_amdgcn_global_load_lds(
        (const __attribute__((address_space(1))) unsigned int*)g,
        (__attribute__((address_space(3))) unsigned int*)l, 16, 0, 0);
}

// Stage a R x 64 bf16 tile with XOR chunk swizzle: LDS chunk (r,c) holds global
// chunk (r, c^(r&7)). Measured (round 1): SQ_LDS_BANK_CONFLICT == 0.
__device__ inline void stage_sw(__bf16* S, const __bf16* G, int row0, int K, int k0,
                                int tid, int nchunks) {
#pragma unroll
    for (int ci = tid; ci < nchunks; ci += 256) {
        const int r  = ci >> 3;
        const int c  = ci & 7;
        const int cg = c ^ (r & 7);
        const char* g = (const char*)G + ((size_t)(row0 + r) * K + k0 + cg * 8) * 2;
        async16(g, (char*)S + ci * 16);
    }
}

// Swizzled fragment read: global chunk (r, cfrag) lives at LDS chunk cfrag^(r&7).
__device__ inline bf16x8 frag_sw(const __bf16* S, int r, int cfrag) {
    const int c = cfrag ^ (r & 7);
    return *(const bf16x8*)(S + r * 64 + c * 8);
}

// fp32 -> bf16 hi (+ optional lo). blockIdx.y selects {x, w_qkv, w_out}.
// w_out path (y==2) additionally permutes input-dim columns within each
// 64-block to match the q/k/v/ao head-dim permutation.
__global__ __launch_bounds__(256) void split_mat(
    const float* __restrict__ s0, __bf16* __restrict__ h0, __bf16* __restrict__ l0, int n0,
    const float* __restrict__ s1, __bf16* __restrict__ h1, __bf16* __restrict__ l1, int n1,
    const float* __restrict__ s2, __bf16* __restrict__ h2, __bf16* __restrict__ l2, int n2)
{
    const float* s; __bf16* h; __bf16* l; int n;
    if (blockIdx.y == 0)      { s = s0; h = h0; l = l0; n = n0; }
    else if (blockIdx.y == 1) { s = s1; h = h1; l = l1; n = n1; }
    else                      { s = s2; h = h2; l = l2; n = n2; }
    const int base = (blockIdx.x * 256 + threadIdx.x) * 8;
    if (base >= n) return;

    float buf[8];
    if (blockIdx.y == 2) {
        // permuted gather: position p holds source d(p) = 16*(p&3) + (p>>2)
#pragma unroll
        for (int m = 0; m < 8; m++) {
            const int p   = base + m;
            const int src = (p & ~63) + (((p & 63) >> 2) + 16 * (p & 3));
            buf[m] = s[src];
        }
    } else {
        float4 a = ((const float4*)(s + base))[0];
        float4 b = ((const float4*)(s + base))[1];
        buf[0] = a.x; buf[1] = a.y; buf[2] = a.z; buf[3] = a.w;
        buf[4] = b.x; buf[5] = b.y; buf[6] = b.z; buf[7] = b.w;
    }

    bf16x8 hv, lv;
#pragma unroll
    for (int j = 0; j < 8; j++) {
        __bf16 hb = (__bf16)buf[j];
        hv[j] = hb;
        lv[j] = (__bf16)(buf[j] - (float)hb);
    }
    *(bf16x8*)(h + base) = hv;
    if (l) *(bf16x8*)(l + base) = lv;
}

// QKV projection: C = A*W^T + bias (bf16 MFMA), fused QK-norm, permuted
// scatter into [B,H,N,64]. TN=128, grid 768 (measured-best geometry).
// K-loop: double-buffered BK=64 with COUNTED-vmcnt raw barriers — prefetch
// loads stay in flight across the lead barrier; vmcnt(0) only on final step.
__global__ __launch_bounds__(256) void gemm_qkv(
    const __bf16* __restrict__ A, const __bf16* __restrict__ W,
    const float* __restrict__ bias,
    __bf16* __restrict__ q, __bf16* __restrict__ k, __bf16* __restrict__ v,
    int M, int N, int K)
{
    __shared__ __bf16 sA[2][TM * BK];
    __shared__ __bf16 sW[2][TM * BK];

    const int tid  = threadIdx.x;
    const int lane = tid & 63;
    const int wave = tid >> 6;
    const int bm = blockIdx.y * TM;
    const int bn = blockIdx.x * 128;
    const int wm = (wave >> 1) * 64;
    const int wn = (wave & 1) * 64;
    const int frow = lane & 15;

    f32x4 acc[4][4] = {};

    // prologue: stage buf0 (4+4 = 8 loads/thread), no wait yet
    stage_sw(sA[0], A, bm, K, 0, tid, TM * 8);
    stage_sw(sW[0], W, bn, K, 0, tid, TM * 8);

    int cur = 0;
    for (int k0 = 0; k0 < K; k0 += BK) {
        if (k0 + BK < K) {
            stage_sw(sA[cur ^ 1], A, bm, K, k0 + BK, tid, TM * 8);
            stage_sw(sW[cur ^ 1], W, bn, K, k0 + BK, tid, TM * 8);
            LEAD_VMBAR(8);   // oldest 8 (buf[cur]) landed; prefetch in flight
        } else {
            LEAD_VMBAR(0);   // final step: drain
        }
        __builtin_amdgcn_s_setprio(1);
#pragma unroll
        for (int half = 0; half < 2; half++) {
            const int cf = half * 4 + (lane >> 4);
            bf16x8 aF[4], bF[4];
#pragma unroll
            for (int t = 0; t < 4; t++) {
                aF[t] = frag_sw(sA[cur], wm + t * 16 + frow, cf);
                bF[t] = frag_sw(sW[cur], wn + t * 16 + frow, cf);
            }
#pragma unroll
            for (int i = 0; i < 4; i++)
#pragma unroll
                for (int j = 0; j < 4; j++)
                    acc[i][j] = __builtin_amdgcn_mfma_f32_16x16x32_bf16(aF[i], bF[j], acc[i][j], 0, 0, 0);
        }
        __builtin_amdgcn_s_setprio(0);
        TRAIL_BAR();         // reads of buf[cur] done -> safe to overwrite
        cur ^= 1;
    }

    // wave's 64-col window = exactly one (tensor t, head h)
    const int col0 = bn + wn;
    const int t  = col0 >> 10;            // 0=q 1=k 2=v
    const int h  = (col0 & 1023) >> 6;

    float bv[4];
#pragma unroll
    for (int j = 0; j < 4; j++) bv[j] = bias[col0 + j * 16 + (lane & 15)];

    // fused QK-norm: per output row, 1/(||row||+eps)
    float inv_n[4][4];
    if (t < 2) {
#pragma unroll
        for (int i = 0; i < 4; i++)
#pragma unroll
            for (int r = 0; r < 4; r++) {
                float ss = 0.f;
#pragma unroll
                for (int j = 0; j < 4; j++) {
                    float val = acc[i][j][r] + bv[j];
                    ss = fmaf(val, val, ss);
                }
                ss += __shfl_xor(ss, 1);
                ss += __shfl_xor(ss, 2);
                ss += __shfl_xor(ss, 4);
                ss += __shfl_xor(ss, 8);
                inv_n[i][r] = 1.0f / (sqrtf(ss) + 1e-6f);
            }
    }

    // Permuted store: lane c's four j-values (dims j*16+c) are contiguous at
    // positions 4c..4c+3 -> one bf16x4 per (i,r). Wave store = 4 x 128B runs.
    __bf16* dstbase = (t == 0) ? q : (t == 1) ? k : v;
    const int c4 = (lane & 15) * 4;
#pragma unroll
    for (int i = 0; i < 4; i++) {
        const int gmBase = bm + wm + i * 16 + (lane >> 4) * 4;
#pragma unroll
        for (int r = 0; r < 4; r++) {
            const int gm = gmBase + r;
            bf16x4 ov;
#pragma unroll
            for (int j = 0; j < 4; j++) {
                float val = acc[i][j][r] + bv[j];
                if (t < 2) val *= inv_n[i][r];
                ov[j] = (__bf16)val;
            }
            const int b  = gm >> 11;
            const int ii = gm & 2047;
            *(bf16x4*)(dstbase + (((size_t)(b * 16 + h) * 2048) + ii) * 64 + c4) = ov;
        }
    }
}

// Out projection: C = A(Wh+Wl)^T + bias, A bf16 (2-term), fp32 out.
// TM=128, TN=64 -> 512 blocks (2/CU). Wave owns 64x32.
// Same counted-vmcnt double-buffered K-loop (4+2+2 = 8 loads/thread).
__global__ __launch_bounds__(256) void gemm_out(
    const __bf16* __restrict__ A,
    const __bf16* __restrict__ Wh, const __bf16* __restrict__ Wl,
    const float* __restrict__ bias, float* __restrict__ C,
    int M, int N, int K)
{
    __shared__ __bf16 sA[2][TM * BK];
    __shared__ __bf16 sWh[2][64 * BK];
    __shared__ __bf16 sWl[2][64 * BK];

    const int tid  = threadIdx.x;
    const int lane = tid & 63;
    const int wave = tid >> 6;
    const int bm = blockIdx.y * TM;
    const int bn = blockIdx.x * 64;
    const int wm = (wave >> 1) * 64;
    const int wn = (wave & 1) * 32;
    const int frow = lane & 15;

    f32x4 acc[4][2] = {};

    stage_sw(sA[0],  A,  bm, K, 0, tid, TM * 8);
    stage_sw(sWh[0], Wh, bn, K, 0, tid, 64 * 8);
    stage_sw(sWl[0], Wl, bn, K, 0, tid, 64 * 8);

    int cur = 0;
    for (int k0 = 0; k0 < K; k0 += BK) {
        if (k0 + BK < K) {
            stage_sw(sA[cur ^ 1],  A,  bm, K, k0 + BK, tid, TM * 8);
            stage_sw(sWh[cur ^ 1], Wh, bn, K, k0 + BK, tid, 64 * 8);
            stage_sw(sWl[cur ^ 1], Wl, bn, K, k0 + BK, tid, 64 * 8);
            LEAD_VMBAR(8);
        } else {
            LEAD_VMBAR(0);
        }
        __builtin_amdgcn_s_setprio(1);
#pragma unroll
        for (int half = 0; half < 2; half++) {
            const int cf = half * 4 + (lane >> 4);
            bf16x8 aH[4], bH[2], bL[2];
#pragma unroll
            for (int t = 0; t < 4; t++)
                aH[t] = frag_sw(sA[cur], wm + t * 16 + frow, cf);
#pragma unroll
            for (int t = 0; t < 2; t++) {
                bH[t] = frag_sw(sWh[cur], wn + t * 16 + frow, cf);
                bL[t] = frag_sw(sWl[cur], wn + t * 16 + frow, cf);
            }
#pragma unroll
            for (int i = 0; i < 4; i++)
#pragma unroll
                for (int j = 0; j < 2; j++) {
                    acc[i][j] = __builtin_amdgcn_mfma_f32_16x16x32_bf16(aH[i], bH[j], acc[i][j], 0, 0, 0);
                    acc[i][j] = __builtin_amdgcn_mfma_f32_16x16x32_bf16(aH[i], bL[j], acc[i][j], 0, 0, 0);
                }
        }
        __builtin_amdgcn_s_setprio(0);
        TRAIL_BAR();
        cur ^= 1;
    }

#pragma unroll
    for (int i = 0; i < 4; i++) {
        const int gmBase = bm + wm + i * 16 + (lane >> 4) * 4;
#pragma unroll
        for (int j = 0; j < 2; j++) {
            const int gn = bn + wn + j * 16 + (lane & 15);
            const float bvj = bias[gn];
#pragma unroll
            for (int r = 0; r < 4; r++)
                C[(size_t)(gmBase + r) * N + gn] = acc[i][j][r] + bvj;
        }
    }
}

// Dilated attention: 8 rows per wave; lane group g=lane>>3 owns row i0+g,
// lane&7 owns 8 head-dims (bf16x8, 16B loads). q,k,v: [B,H,N,64] bf16
// (q,k normalized; head-dims permuted — attention is dim-order-invariant,
// ao inherits the permuted order consumed consistently by gemm_out).
__global__ __launch_bounds__(256) void attn_sparse(
    const __bf16* __restrict__ q, const __bf16* __restrict__ k,
    const __bf16* __restrict__ v, __bf16* __restrict__ ao /*[B,N,D] bf16*/)
{
    const int wid  = blockIdx.x * 4 + (threadIdx.x >> 6);
    const int lane = threadIdx.x & 63;
    const int g    = lane >> 3;          // row group 0..7
    const int ld   = (lane & 7) * 8;     // dim offset (8 dims per lane)

    const int bh = wid >> 8;             // 256 wave-tasks per (b,h) = 2048/8
    const int i  = (wid & 255) * 8 + g;  // this lane-group's row

    const __bf16* qb = q + (size_t)bh * 2048 * 64;
    const __bf16* kb = k + (size_t)bh * 2048 * 64;
    const __bf16* vb = v + (size_t)bh * 2048 * 64;

    bf16x8 qv = *(const bf16x8*)(qb + (size_t)i * 64 + ld);
    float qf[8];
#pragma unroll
    for (int e = 0; e < 8; e++) qf[e] = (float)qv[e];

    float s[17];
#pragma unroll
    for (int t = 0; t < 17; t++) {
        const int j = i + 2 * t - 16;
        const bool valid = (j >= 0) && (j < 2048);
        const int jc = valid ? j : i;
        bf16x8 kv = *(const bf16x8*)(kb + (size_t)jc * 64 + ld);
        float prod = qf[0] * (float)kv[0];
#pragma unroll
        for (int e = 1; e < 8; e++) prod = fmaf(qf[e], (float)kv[e], prod);
        prod += __shfl_xor(prod, 1);
        prod += __shfl_xor(prod, 2);
        prod += __shfl_xor(prod, 4);
        s[t] = valid ? prod : -INFINITY;
    }

    float m = s[0];
#pragma unroll
    for (int t = 1; t < 17; t++) m = fmaxf(m, s[t]);
    float denom = 0.f, p[17];
#pragma unroll
    for (int t = 0; t < 17; t++) { p[t] = __expf(s[t] - m); denom += p[t]; }
    const float inv = 1.0f / denom;

    float a[8] = {};
#pragma unroll
    for (int t = 0; t < 17; t++) {
        const int j = i + 2 * t - 16;
        const int jc = (j >= 0 && j < 2048) ? j : i;   // p[t]==0 when invalid
        bf16x8 vv = *(const bf16x8*)(vb + (size_t)jc * 64 + ld);
#pragma unroll
        for (int e = 0; e < 8; e++) a[e] = fmaf(p[t], (float)vv[e], a[e]);
    }

    const int b = bh >> 4, h = bh & 15;
    bf16x8 o;
#pragma unroll
    for (int e = 0; e < 8; e++) o[e] = (__bf16)(a[e] * inv);
    *(bf16x8*)(ao + ((size_t)(b * 2048 + i)) * 1024 + h * 64 + ld) = o;
}

extern "C" void kernel_launch(void* const* d_in, const int* in_sizes, int n_in,
                              void* d_out, int out_size, void* d_ws, size_t ws_size,
                              hipStream_t stream)
{
    const float* x     = (const float*)d_in[0];  // [2,2048,1024]
    const float* w_qkv = (const float*)d_in[1];  // [3072,1024]
    const float* b_qkv = (const float*)d_in[2];  // [3072]
    const float* w_out = (const float*)d_in[3];  // [1024,1024]
    const float* b_out = (const float*)d_in[4];  // [1024]
    float* out = (float*)d_out;                  // [2,2048,1024]

    const int Dn = 1024;
    const int M  = 4096;
    const int nx = 4194304, nwq = 3145728, nwo = 1048576;

    char* p = (char*)d_ws;
    __bf16* q   = (__bf16*)p;  p += (size_t)nx * 2;   // [2,16,2048,64]
    __bf16* kk  = (__bf16*)p;  p += (size_t)nx * 2;
    __bf16* vv  = (__bf16*)p;  p += (size_t)nx * 2;
    __bf16* xh  = (__bf16*)p;  p += (size_t)nx * 2;   // aliased to ao after gemm_qkv
    __bf16* wqh = (__bf16*)p;  p += (size_t)nwq * 2;
    __bf16* woh = (__bf16*)p;  p += (size_t)nwo * 2;
    __bf16* wol = (__bf16*)p;  p += (size_t)nwo * 2;
    __bf16* ao  = xh;

    // 0) x, w_qkv -> bf16 cast; w_out -> hi/lo bf16 split (in-dim permuted)
    {
        dim3 grid(nx / 8 / 256, 3);
        hipLaunchKernelGGL(split_mat, grid, dim3(256), 0, stream,
                           x, xh, (__bf16*)nullptr, nx,
                           w_qkv, wqh, (__bf16*)nullptr, nwq,
                           w_out, woh, wol, nwo);
    }
    // 1) qkv projection + fused qk-norm -> q,k,v bf16 head layout
    {
        dim3 grid(3 * Dn / 128, M / TM);   // 24 x 32 = 768 blocks
        hipLaunchKernelGGL(gemm_qkv, grid, dim3(256), 0, stream,
                           xh, wqh, b_qkv, q, kk, vv, M, 3 * Dn, Dn);
    }
    // 2) sparse dilated attention -> ao bf16 [B,N,D]  (8192 waves)
    hipLaunchKernelGGL(attn_sparse, dim3(2048), dim3(256), 0, stream,
                       q, kk, vv, ao);
    // 3) output projection (2-term) -> fp32 out
    {
        dim3 grid(Dn / 64, M / TM);        // 16 x 32 = 512 blocks
        hipLaunchKernelGGL(gemm_out, grid, dim3(256), 0, stream,
                           ao, woh, wol, b_out, out, M, Dn, Dn);
    }
}

// Round 12
// 164.787 us; speedup vs baseline: 1.0367x; 1.0367x over previous
//
#include <hip/hip_runtime.h>
#include <hip/hip_bf16.h>
#include <math.h>

typedef __bf16 bf16x8 __attribute__((ext_vector_type(8)));
typedef __bf16 bf16x4 __attribute__((ext_vector_type(4)));
typedef float f32x4 __attribute__((ext_vector_type(4)));

#define TM 128
#define BK 128  // bf16 elements per K-tile (16 chunks of 16B per row); 8 K-steps

// ---------------------------------------------------------------------------
// Head-dim permutation: q/k/v/ao store dim d at position p = 4*(d&15)+(d>>4)
// (within each 64-dim head block). Attention is dim-order-invariant, so only
// w_out's input-dim columns must be permuted to match (done in split_mat).
// ---------------------------------------------------------------------------

__device__ inline void async16(const void* g, void* l) {
    __builtin_amdgcn_global_load_lds(
        (const __attribute__((address_space(1))) unsigned int*)g,
        (__attribute__((address_space(3))) unsigned int*)l, 16, 0, 0);
}

// Stage a R x 128 bf16 tile with XOR chunk swizzle: LDS chunk (r,c) holds
// global chunk (r, c^(r&7)), c in 0..15. Wave ds_read_b128 readers hit all
// 32 banks at 2-way (free): bank = (c_lds*4+word)%32, c_lds low-3-bits span
// 0..7 across the 16 lanes of a row-group.
__device__ inline void stage_sw(__bf16* S, const __bf16* G, int row0, int K, int k0,
                                int tid, int nchunks) {
#pragma unroll
    for (int ci = tid; ci < nchunks; ci += 256) {
        const int r  = ci >> 4;
        const int c  = ci & 15;
        const int cg = c ^ (r & 7);
        const char* g = (const char*)G + ((size_t)(row0 + r) * K + k0 + cg * 8) * 2;
        async16(g, (char*)S + ci * 16);
    }
}

// Swizzled fragment read: global chunk (r, cfrag) lives at LDS chunk cfrag^(r&7).
__device__ inline bf16x8 frag_sw(const __bf16* S, int r, int cfrag) {
    const int c = cfrag ^ (r & 7);
    return *(const bf16x8*)(S + r * 128 + c * 8);
}

// fp32 -> bf16 hi (+ optional lo). blockIdx.y selects {x, w_qkv, w_out}.
// w_out path (y==2) additionally permutes input-dim columns within each
// 64-block to match the q/k/v/ao head-dim permutation.
__global__ __launch_bounds__(256) void split_mat(
    const float* __restrict__ s0, __bf16* __restrict__ h0, __bf16* __restrict__ l0, int n0,
    const float* __restrict__ s1, __bf16* __restrict__ h1, __bf16* __restrict__ l1, int n1,
    const float* __restrict__ s2, __bf16* __restrict__ h2, __bf16* __restrict__ l2, int n2)
{
    const float* s; __bf16* h; __bf16* l; int n;
    if (blockIdx.y == 0)      { s = s0; h = h0; l = l0; n = n0; }
    else if (blockIdx.y == 1) { s = s1; h = h1; l = l1; n = n1; }
    else                      { s = s2; h = h2; l = l2; n = n2; }
    const int base = (blockIdx.x * 256 + threadIdx.x) * 8;
    if (base >= n) return;

    float buf[8];
    if (blockIdx.y == 2) {
        // permuted gather: position p holds source d(p) = 16*(p&3) + (p>>2)
#pragma unroll
        for (int m = 0; m < 8; m++) {
            const int p   = base + m;
            const int src = (p & ~63) + (((p & 63) >> 2) + 16 * (p & 3));
            buf[m] = s[src];
        }
    } else {
        float4 a = ((const float4*)(s + base))[0];
        float4 b = ((const float4*)(s + base))[1];
        buf[0] = a.x; buf[1] = a.y; buf[2] = a.z; buf[3] = a.w;
        buf[4] = b.x; buf[5] = b.y; buf[6] = b.z; buf[7] = b.w;
    }

    bf16x8 hv, lv;
#pragma unroll
    for (int j = 0; j < 8; j++) {
        __bf16 hb = (__bf16)buf[j];
        hv[j] = hb;
        lv[j] = (__bf16)(buf[j] - (float)hb);
    }
    *(bf16x8*)(h + base) = hv;
    if (l) *(bf16x8*)(l + base) = lv;
}

// QKV projection: C = A*W^T + bias (bf16 MFMA), fused QK-norm, permuted
// scatter into [B,H,N,64]. TN=128, grid 768 (measured-best geometry).
// BK=128 single-buffer: 8 K-steps (vs 16) — halves the measured ~0.56us
// fixed per-step barrier cost. LDS 64KB -> 2 blocks/CU (measured == 3).
__global__ __launch_bounds__(256) void gemm_qkv(
    const __bf16* __restrict__ A, const __bf16* __restrict__ W,
    const float* __restrict__ bias,
    __bf16* __restrict__ q, __bf16* __restrict__ k, __bf16* __restrict__ v,
    int M, int N, int K)
{
    __shared__ __bf16 sA[TM * BK];
    __shared__ __bf16 sW[TM * BK];

    const int tid  = threadIdx.x;
    const int lane = tid & 63;
    const int wave = tid >> 6;
    const int bm = blockIdx.y * TM;
    const int bn = blockIdx.x * 128;
    const int wm = (wave >> 1) * 64;
    const int wn = (wave & 1) * 64;
    const int frow = lane & 15;

    f32x4 acc[4][4] = {};

    for (int k0 = 0; k0 < K; k0 += BK) {
        stage_sw(sA, A, bm, K, k0, tid, TM * 16);
        stage_sw(sW, W, bn, K, k0, tid, TM * 16);
        __syncthreads();

#pragma unroll
        for (int half = 0; half < 4; half++) {
            const int cf = half * 4 + (lane >> 4);
            bf16x8 aF[4], bF[4];
#pragma unroll
            for (int t = 0; t < 4; t++) {
                aF[t] = frag_sw(sA, wm + t * 16 + frow, cf);
                bF[t] = frag_sw(sW, wn + t * 16 + frow, cf);
            }
#pragma unroll
            for (int i = 0; i < 4; i++)
#pragma unroll
                for (int j = 0; j < 4; j++)
                    acc[i][j] = __builtin_amdgcn_mfma_f32_16x16x32_bf16(aF[i], bF[j], acc[i][j], 0, 0, 0);
        }
        __syncthreads();
    }

    // wave's 64-col window = exactly one (tensor t, head h)
    const int col0 = bn + wn;
    const int t  = col0 >> 10;            // 0=q 1=k 2=v
    const int h  = (col0 & 1023) >> 6;

    float bv[4];
#pragma unroll
    for (int j = 0; j < 4; j++) bv[j] = bias[col0 + j * 16 + (lane & 15)];

    // fused QK-norm: per output row, 1/(||row||+eps)
    float inv_n[4][4];
    if (t < 2) {
#pragma unroll
        for (int i = 0; i < 4; i++)
#pragma unroll
            for (int r = 0; r < 4; r++) {
                float ss = 0.f;
#pragma unroll
                for (int j = 0; j < 4; j++) {
                    float val = acc[i][j][r] + bv[j];
                    ss = fmaf(val, val, ss);
                }
                ss += __shfl_xor(ss, 1);
                ss += __shfl_xor(ss, 2);
                ss += __shfl_xor(ss, 4);
                ss += __shfl_xor(ss, 8);
                inv_n[i][r] = 1.0f / (sqrtf(ss) + 1e-6f);
            }
    }

    // Permuted store: lane c's four j-values (dims j*16+c) are contiguous at
    // positions 4c..4c+3 -> one bf16x4 per (i,r). Wave store = 4 x 128B runs.
    __bf16* dstbase = (t == 0) ? q : (t == 1) ? k : v;
    const int c4 = (lane & 15) * 4;
#pragma unroll
    for (int i = 0; i < 4; i++) {
        const int gmBase = bm + wm + i * 16 + (lane >> 4) * 4;
#pragma unroll
        for (int r = 0; r < 4; r++) {
            const int gm = gmBase + r;
            bf16x4 ov;
#pragma unroll
            for (int j = 0; j < 4; j++) {
                float val = acc[i][j][r] + bv[j];
                if (t < 2) val *= inv_n[i][r];
                ov[j] = (__bf16)val;
            }
            const int b  = gm >> 11;
            const int ii = gm & 2047;
            *(bf16x4*)(dstbase + (((size_t)(b * 16 + h) * 2048) + ii) * 64 + c4) = ov;
        }
    }
}

// Out projection: C = A(Wh+Wl)^T + bias, A bf16 (2-term), fp32 out.
// TM=128, TN=64 -> 512 blocks. Wave owns 64x32. BK=128 single-buffer:
// 8 K-steps. LDS 64KB (32+16+16) -> 2 blocks/CU.
__global__ __launch_bounds__(256) void gemm_out(
    const __bf16* __restrict__ A,
    const __bf16* __restrict__ Wh, const __bf16* __restrict__ Wl,
    const float* __restrict__ bias, float* __restrict__ C,
    int M, int N, int K)
{
    __shared__ __bf16 sA[TM * BK];
    __shared__ __bf16 sWh[64 * BK];
    __shared__ __bf16 sWl[64 * BK];

    const int tid  = threadIdx.x;
    const int lane = tid & 63;
    const int wave = tid >> 6;
    const int bm = blockIdx.y * TM;
    const int bn = blockIdx.x * 64;
    const int wm = (wave >> 1) * 64;
    const int wn = (wave & 1) * 32;
    const int frow = lane & 15;

    f32x4 acc[4][2] = {};

    for (int k0 = 0; k0 < K; k0 += BK) {
        stage_sw(sA,  A,  bm, K, k0, tid, TM * 16);
        stage_sw(sWh, Wh, bn, K, k0, tid, 64 * 16);
        stage_sw(sWl, Wl, bn, K, k0, tid, 64 * 16);
        __syncthreads();

#pragma unroll
        for (int half = 0; half < 4; half++) {
            const int cf = half * 4 + (lane >> 4);
            bf16x8 aH[4], bH[2], bL[2];
#pragma unroll
            for (int t = 0; t < 4; t++)
                aH[t] = frag_sw(sA, wm + t * 16 + frow, cf);
#pragma unroll
            for (int t = 0; t < 2; t++) {
                bH[t] = frag_sw(sWh, wn + t * 16 + frow, cf);
                bL[t] = frag_sw(sWl, wn + t * 16 + frow, cf);
            }
#pragma unroll
            for (int i = 0; i < 4; i++)
#pragma unroll
                for (int j = 0; j < 2; j++) {
                    acc[i][j] = __builtin_amdgcn_mfma_f32_16x16x32_bf16(aH[i], bH[j], acc[i][j], 0, 0, 0);
                    acc[i][j] = __builtin_amdgcn_mfma_f32_16x16x32_bf16(aH[i], bL[j], acc[i][j], 0, 0, 0);
                }
        }
        __syncthreads();
    }

#pragma unroll
    for (int i = 0; i < 4; i++) {
        const int gmBase = bm + wm + i * 16 + (lane >> 4) * 4;
#pragma unroll
        for (int j = 0; j < 2; j++) {
            const int gn = bn + wn + j * 16 + (lane & 15);
            const float bvj = bias[gn];
#pragma unroll
            for (int r = 0; r < 4; r++)
                C[(size_t)(gmBase + r) * N + gn] = acc[i][j][r] + bvj;
        }
    }
}

// Dilated attention: 8 rows per wave; lane group g=lane>>3 owns row i0+g,
// lane&7 owns 8 head-dims (bf16x8, 16B loads). q,k,v: [B,H,N,64] bf16
// (q,k normalized; head-dims permuted — attention is dim-order-invariant,
// ao inherits the permuted order consumed consistently by gemm_out).
__global__ __launch_bounds__(256) void attn_sparse(
    const __bf16* __restrict__ q, const __bf16* __restrict__ k,
    const __bf16* __restrict__ v, __bf16* __restrict__ ao /*[B,N,D] bf16*/)
{
    const int wid  = blockIdx.x * 4 + (threadIdx.x >> 6);
    const int lane = threadIdx.x & 63;
    const int g    = lane >> 3;          // row group 0..7
    const int ld   = (lane & 7) * 8;     // dim offset (8 dims per lane)

    const int bh = wid >> 8;             // 256 wave-tasks per (b,h) = 2048/8
    const int i  = (wid & 255) * 8 + g;  // this lane-group's row

    const __bf16* qb = q + (size_t)bh * 2048 * 64;
    const __bf16* kb = k + (size_t)bh * 2048 * 64;
    const __bf16* vb = v + (size_t)bh * 2048 * 64;

    bf16x8 qv = *(const bf16x8*)(qb + (size_t)i * 64 + ld);
    float qf[8];
#pragma unroll
    for (int e = 0; e < 8; e++) qf[e] = (float)qv[e];

    float s[17];
#pragma unroll
    for (int t = 0; t < 17; t++) {
        const int j = i + 2 * t - 16;
        const bool valid = (j >= 0) && (j < 2048);
        const int jc = valid ? j : i;
        bf16x8 kv = *(const bf16x8*)(kb + (size_t)jc * 64 + ld);
        float prod = qf[0] * (float)kv[0];
#pragma unroll
        for (int e = 1; e < 8; e++) prod = fmaf(qf[e], (float)kv[e], prod);
        prod += __shfl_xor(prod, 1);
        prod += __shfl_xor(prod, 2);
        prod += __shfl_xor(prod, 4);
        s[t] = valid ? prod : -INFINITY;
    }

    float m = s[0];
#pragma unroll
    for (int t = 1; t < 17; t++) m = fmaxf(m, s[t]);
    float denom = 0.f, p[17];
#pragma unroll
    for (int t = 0; t < 17; t++) { p[t] = __expf(s[t] - m); denom += p[t]; }
    const float inv = 1.0f / denom;

    float a[8] = {};
#pragma unroll
    for (int t = 0; t < 17; t++) {
        const int j = i + 2 * t - 16;
        const int jc = (j >= 0 && j < 2048) ? j : i;   // p[t]==0 when invalid
        bf16x8 vv = *(const bf16x8*)(vb + (size_t)jc * 64 + ld);
#pragma unroll
        for (int e = 0; e < 8; e++) a[e] = fmaf(p[t], (float)vv[e], a[e]);
    }

    const int b = bh >> 4, h = bh & 15;
    bf16x8 o;
#pragma unroll
    for (int e = 0; e < 8; e++) o[e] = (__bf16)(a[e] * inv);
    *(bf16x8*)(ao + ((size_t)(b * 2048 + i)) * 1024 + h * 64 + ld) = o;
}

extern "C" void kernel_launch(void* const* d_in, const int* in_sizes, int n_in,
                              void* d_out, int out_size, void* d_ws, size_t ws_size,
                              hipStream_t stream)
{
    const float* x     = (const float*)d_in[0];  // [2,2048,1024]
    const float* w_qkv = (const float*)d_in[1];  // [3072,1024]
    const float* b_qkv = (const float*)d_in[2];  // [3072]
    const float* w_out = (const float*)d_in[3];  // [1024,1024]
    const float* b_out = (const float*)d_in[4];  // [1024]
    float* out = (float*)d_out;                  // [2,2048,1024]

    const int Dn = 1024;
    const int M  = 4096;
    const int nx = 4194304, nwq = 3145728, nwo = 1048576;

    char* p = (char*)d_ws;
    __bf16* q   = (__bf16*)p;  p += (size_t)nx * 2;   // [2,16,2048,64]
    __bf16* kk  = (__bf16*)p;  p += (size_t)nx * 2;
    __bf16* vv  = (__bf16*)p;  p += (size_t)nx * 2;
    __bf16* xh  = (__bf16*)p;  p += (size_t)nx * 2;   // aliased to ao after gemm_qkv
    __bf16* wqh = (__bf16*)p;  p += (size_t)nwq * 2;
    __bf16* woh = (__bf16*)p;  p += (size_t)nwo * 2;
    __bf16* wol = (__bf16*)p;  p += (size_t)nwo * 2;
    __bf16* ao  = xh;

    // 0) x, w_qkv -> bf16 cast; w_out -> hi/lo bf16 split (in-dim permuted)
    {
        dim3 grid(nx / 8 / 256, 3);
        hipLaunchKernelGGL(split_mat, grid, dim3(256), 0, stream,
                           x, xh, (__bf16*)nullptr, nx,
                           w_qkv, wqh, (__bf16*)nullptr, nwq,
                           w_out, woh, wol, nwo);
    }
    // 1) qkv projection + fused qk-norm -> q,k,v bf16 head layout
    {
        dim3 grid(3 * Dn / 128, M / TM);   // 24 x 32 = 768 blocks
        hipLaunchKernelGGL(gemm_qkv, grid, dim3(256), 0, stream,
                           xh, wqh, b_qkv, q, kk, vv, M, 3 * Dn, Dn);
    }
    // 2) sparse dilated attention -> ao bf16 [B,N,D]  (8192 waves)
    hipLaunchKernelGGL(attn_sparse, dim3(2048), dim3(256), 0, stream,
                       q, kk, vv, ao);
    // 3) output projection (2-term) -> fp32 out
    {
        dim3 grid(Dn / 64, M / TM);        // 16 x 32 = 512 blocks
        hipLaunchKernelGGL(gemm_out, grid, dim3(256), 0, stream,
                           ao, woh, wol, b_out, out, M, Dn, Dn);
    }
}

// Round 13
// 163.371 us; speedup vs baseline: 1.0457x; 1.0087x over previous
//
#include <hip/hip_runtime.h>
#include <hip/hip_bf16.h>
#include <math.h>

typedef __bf16 bf16x8 __attribute__((ext_vector_type(8)));
typedef __bf16 bf16x4 __attribute__((ext_vector_type(4)));
typedef float f32x4 __attribute__((ext_vector_type(4)));

#define TM 128
#define BK 128  // K-tile = 2 x 64-col half-tiles, each in the round-1-proven layout

// ---------------------------------------------------------------------------
// Head-dim permutation: q/k/v/ao store dim d at position p = 4*(d&15)+(d>>4)
// (within each 64-dim head block). Attention is dim-order-invariant, so only
// w_out's input-dim columns must be permuted to match (done in split_mat).
// ---------------------------------------------------------------------------

__device__ inline void async16(const void* g, void* l) {
    __builtin_amdgcn_global_load_lds(
        (const __attribute__((address_space(1))) unsigned int*)g,
        (__attribute__((address_space(3))) unsigned int*)l, 16, 0, 0);
}

// Stage a R x 64 bf16 tile with XOR chunk swizzle: LDS chunk (r,c) holds global
// chunk (r, c^(r&7)). ROUND-1 LAYOUT: measured SQ_LDS_BANK_CONFLICT == 0.
// (The fused 128-wide layout of round 12 measured 3.15M conflicts; a 128-wide
// K-tile is now stored as TWO of these 64-wide buffers.)
__device__ inline void stage_sw(__bf16* S, const __bf16* G, int row0, int K, int k0,
                                int tid, int nchunks) {
#pragma unroll
    for (int ci = tid; ci < nchunks; ci += 256) {
        const int r  = ci >> 3;
        const int c  = ci & 7;
        const int cg = c ^ (r & 7);
        const char* g = (const char*)G + ((size_t)(row0 + r) * K + k0 + cg * 8) * 2;
        async16(g, (char*)S + ci * 16);
    }
}

// Swizzled fragment read: global chunk (r, cfrag) lives at LDS chunk cfrag^(r&7).
__device__ inline bf16x8 frag_sw(const __bf16* S, int r, int cfrag) {
    const int c = cfrag ^ (r & 7);
    return *(const bf16x8*)(S + r * 64 + c * 8);
}

// fp32 -> bf16 hi (+ optional lo). blockIdx.y selects {x, w_qkv, w_out}.
// w_out path (y==2) additionally permutes input-dim columns within each
// 64-block to match the q/k/v/ao head-dim permutation.
__global__ __launch_bounds__(256) void split_mat(
    const float* __restrict__ s0, __bf16* __restrict__ h0, __bf16* __restrict__ l0, int n0,
    const float* __restrict__ s1, __bf16* __restrict__ h1, __bf16* __restrict__ l1, int n1,
    const float* __restrict__ s2, __bf16* __restrict__ h2, __bf16* __restrict__ l2, int n2)
{
    const float* s; __bf16* h; __bf16* l; int n;
    if (blockIdx.y == 0)      { s = s0; h = h0; l = l0; n = n0; }
    else if (blockIdx.y == 1) { s = s1; h = h1; l = l1; n = n1; }
    else                      { s = s2; h = h2; l = l2; n = n2; }
    const int base = (blockIdx.x * 256 + threadIdx.x) * 8;
    if (base >= n) return;

    float buf[8];
    if (blockIdx.y == 2) {
        // permuted gather: position p holds source d(p) = 16*(p&3) + (p>>2)
#pragma unroll
        for (int m = 0; m < 8; m++) {
            const int p   = base + m;
            const int src = (p & ~63) + (((p & 63) >> 2) + 16 * (p & 3));
            buf[m] = s[src];
        }
    } else {
        float4 a = ((const float4*)(s + base))[0];
        float4 b = ((const float4*)(s + base))[1];
        buf[0] = a.x; buf[1] = a.y; buf[2] = a.z; buf[3] = a.w;
        buf[4] = b.x; buf[5] = b.y; buf[6] = b.z; buf[7] = b.w;
    }

    bf16x8 hv, lv;
#pragma unroll
    for (int j = 0; j < 8; j++) {
        __bf16 hb = (__bf16)buf[j];
        hv[j] = hb;
        lv[j] = (__bf16)(buf[j] - (float)hb);
    }
    *(bf16x8*)(h + base) = hv;
    if (l) *(bf16x8*)(l + base) = lv;
}

// QKV projection: C = A*W^T + bias (bf16 MFMA), fused QK-norm, permuted
// scatter into [B,H,N,64]. TN=128, grid 768 (measured-best geometry).
// BK=128 single-buffer (8 K-steps, round-12 win) with the K-tile stored as
// TWO 64-col half-buffers in the round-1 0-conflict layout (round-12's fused
// 128-wide layout measured 3.15M bank conflicts). LDS 64KB -> 2 blocks/CU.
__global__ __launch_bounds__(256) void gemm_qkv(
    const __bf16* __restrict__ A, const __bf16* __restrict__ W,
    const float* __restrict__ bias,
    __bf16* __restrict__ q, __bf16* __restrict__ k, __bf16* __restrict__ v,
    int M, int N, int K)
{
    __shared__ __bf16 sA[2][TM * 64];
    __shared__ __bf16 sW[2][TM * 64];

    const int tid  = threadIdx.x;
    const int lane = tid & 63;
    const int wave = tid >> 6;
    const int bm = blockIdx.y * TM;
    const int bn = blockIdx.x * 128;
    const int wm = (wave >> 1) * 64;
    const int wn = (wave & 1) * 64;
    const int frow = lane & 15;

    f32x4 acc[4][4] = {};

    for (int k0 = 0; k0 < K; k0 += BK) {
        stage_sw(sA[0], A, bm, K, k0,      tid, TM * 8);
        stage_sw(sA[1], A, bm, K, k0 + 64, tid, TM * 8);
        stage_sw(sW[0], W, bn, K, k0,      tid, TM * 8);
        stage_sw(sW[1], W, bn, K, k0 + 64, tid, TM * 8);
        __syncthreads();

#pragma unroll
        for (int half = 0; half < 4; half++) {
            const __bf16* bA = sA[half >> 1];     // compile-time per half
            const __bf16* bW = sW[half >> 1];
            const int cf = (half & 1) * 4 + (lane >> 4);
            bf16x8 aF[4], bF[4];
#pragma unroll
            for (int t = 0; t < 4; t++) {
                aF[t] = frag_sw(bA, wm + t * 16 + frow, cf);
                bF[t] = frag_sw(bW, wn + t * 16 + frow, cf);
            }
#pragma unroll
            for (int i = 0; i < 4; i++)
#pragma unroll
                for (int j = 0; j < 4; j++)
                    acc[i][j] = __builtin_amdgcn_mfma_f32_16x16x32_bf16(aF[i], bF[j], acc[i][j], 0, 0, 0);
        }
        __syncthreads();
    }

    // wave's 64-col window = exactly one (tensor t, head h)
    const int col0 = bn + wn;
    const int t  = col0 >> 10;            // 0=q 1=k 2=v
    const int h  = (col0 & 1023) >> 6;

    float bv[4];
#pragma unroll
    for (int j = 0; j < 4; j++) bv[j] = bias[col0 + j * 16 + (lane & 15)];

    // fused QK-norm: per output row, 1/(||row||+eps)
    float inv_n[4][4];
    if (t < 2) {
#pragma unroll
        for (int i = 0; i < 4; i++)
#pragma unroll
            for (int r = 0; r < 4; r++) {
                float ss = 0.f;
#pragma unroll
                for (int j = 0; j < 4; j++) {
                    float val = acc[i][j][r] + bv[j];
                    ss = fmaf(val, val, ss);
                }
                ss += __shfl_xor(ss, 1);
                ss += __shfl_xor(ss, 2);
                ss += __shfl_xor(ss, 4);
                ss += __shfl_xor(ss, 8);
                inv_n[i][r] = 1.0f / (sqrtf(ss) + 1e-6f);
            }
    }

    // Permuted store: lane c's four j-values (dims j*16+c) are contiguous at
    // positions 4c..4c+3 -> one bf16x4 per (i,r). Wave store = 4 x 128B runs.
    __bf16* dstbase = (t == 0) ? q : (t == 1) ? k : v;
    const int c4 = (lane & 15) * 4;
#pragma unroll
    for (int i = 0; i < 4; i++) {
        const int gmBase = bm + wm + i * 16 + (lane >> 4) * 4;
#pragma unroll
        for (int r = 0; r < 4; r++) {
            const int gm = gmBase + r;
            bf16x4 ov;
#pragma unroll
            for (int j = 0; j < 4; j++) {
                float val = acc[i][j][r] + bv[j];
                if (t < 2) val *= inv_n[i][r];
                ov[j] = (__bf16)val;
            }
            const int b  = gm >> 11;
            const int ii = gm & 2047;
            *(bf16x4*)(dstbase + (((size_t)(b * 16 + h) * 2048) + ii) * 64 + c4) = ov;
        }
    }
}

// Out projection: C = A(Wh+Wl)^T + bias, A bf16 (2-term), fp32 out.
// TM=128, TN=64 -> 512 blocks. Wave owns 64x32. BK=128 as two 64-col
// half-buffers (0-conflict layout). LDS 64KB (32+16+16) -> 2 blocks/CU.
__global__ __launch_bounds__(256) void gemm_out(
    const __bf16* __restrict__ A,
    const __bf16* __restrict__ Wh, const __bf16* __restrict__ Wl,
    const float* __restrict__ bias, float* __restrict__ C,
    int M, int N, int K)
{
    __shared__ __bf16 sA[2][TM * 64];
    __shared__ __bf16 sWh[2][64 * 64];
    __shared__ __bf16 sWl[2][64 * 64];

    const int tid  = threadIdx.x;
    const int lane = tid & 63;
    const int wave = tid >> 6;
    const int bm = blockIdx.y * TM;
    const int bn = blockIdx.x * 64;
    const int wm = (wave >> 1) * 64;
    const int wn = (wave & 1) * 32;
    const int frow = lane & 15;

    f32x4 acc[4][2] = {};

    for (int k0 = 0; k0 < K; k0 += BK) {
        stage_sw(sA[0],  A,  bm, K, k0,      tid, TM * 8);
        stage_sw(sA[1],  A,  bm, K, k0 + 64, tid, TM * 8);
        stage_sw(sWh[0], Wh, bn, K, k0,      tid, 64 * 8);
        stage_sw(sWh[1], Wh, bn, K, k0 + 64, tid, 64 * 8);
        stage_sw(sWl[0], Wl, bn, K, k0,      tid, 64 * 8);
        stage_sw(sWl[1], Wl, bn, K, k0 + 64, tid, 64 * 8);
        __syncthreads();

#pragma unroll
        for (int half = 0; half < 4; half++) {
            const __bf16* bA  = sA[half >> 1];
            const __bf16* bWh = sWh[half >> 1];
            const __bf16* bWl = sWl[half >> 1];
            const int cf = (half & 1) * 4 + (lane >> 4);
            bf16x8 aH[4], bH[2], bL[2];
#pragma unroll
            for (int t = 0; t < 4; t++)
                aH[t] = frag_sw(bA, wm + t * 16 + frow, cf);
#pragma unroll
            for (int t = 0; t < 2; t++) {
                bH[t] = frag_sw(bWh, wn + t * 16 + frow, cf);
                bL[t] = frag_sw(bWl, wn + t * 16 + frow, cf);
            }
#pragma unroll
            for (int i = 0; i < 4; i++)
#pragma unroll
                for (int j = 0; j < 2; j++) {
                    acc[i][j] = __builtin_amdgcn_mfma_f32_16x16x32_bf16(aH[i], bH[j], acc[i][j], 0, 0, 0);
                    acc[i][j] = __builtin_amdgcn_mfma_f32_16x16x32_bf16(aH[i], bL[j], acc[i][j], 0, 0, 0);
                }
        }
        __syncthreads();
    }

#pragma unroll
    for (int i = 0; i < 4; i++) {
        const int gmBase = bm + wm + i * 16 + (lane >> 4) * 4;
#pragma unroll
        for (int j = 0; j < 2; j++) {
            const int gn = bn + wn + j * 16 + (lane & 15);
            const float bvj = bias[gn];
#pragma unroll
            for (int r = 0; r < 4; r++)
                C[(size_t)(gmBase + r) * N + gn] = acc[i][j][r] + bvj;
        }
    }
}

// Dilated attention: 8 rows per wave; lane group g=lane>>3 owns row i0+g,
// lane&7 owns 8 head-dims (bf16x8, 16B loads). q,k,v: [B,H,N,64] bf16
// (q,k normalized; head-dims permuted — attention is dim-order-invariant,
// ao inherits the permuted order consumed consistently by gemm_out).
__global__ __launch_bounds__(256) void attn_sparse(
    const __bf16* __restrict__ q, const __bf16* __restrict__ k,
    const __bf16* __restrict__ v, __bf16* __restrict__ ao /*[B,N,D] bf16*/)
{
    const int wid  = blockIdx.x * 4 + (threadIdx.x >> 6);
    const int lane = threadIdx.x & 63;
    const int g    = lane >> 3;          // row group 0..7
    const int ld   = (lane & 7) * 8;     // dim offset (8 dims per lane)

    const int bh = wid >> 8;             // 256 wave-tasks per (b,h) = 2048/8
    const int i  = (wid & 255) * 8 + g;  // this lane-group's row

    const __bf16* qb = q + (size_t)bh * 2048 * 64;
    const __bf16* kb = k + (size_t)bh * 2048 * 64;
    const __bf16* vb = v + (size_t)bh * 2048 * 64;

    bf16x8 qv = *(const bf16x8*)(qb + (size_t)i * 64 + ld);
    float qf[8];
#pragma unroll
    for (int e = 0; e < 8; e++) qf[e] = (float)qv[e];

    float s[17];
#pragma unroll
    for (int t = 0; t < 17; t++) {
        const int j = i + 2 * t - 16;
        const bool valid = (j >= 0) && (j < 2048);
        const int jc = valid ? j : i;
        bf16x8 kv = *(const bf16x8*)(kb + (size_t)jc * 64 + ld);
        float prod = qf[0] * (float)kv[0];
#pragma unroll
        for (int e = 1; e < 8; e++) prod = fmaf(qf[e], (float)kv[e], prod);
        prod += __shfl_xor(prod, 1);
        prod += __shfl_xor(prod, 2);
        prod += __shfl_xor(prod, 4);
        s[t] = valid ? prod : -INFINITY;
    }

    float m = s[0];
#pragma unroll
    for (int t = 1; t < 17; t++) m = fmaxf(m, s[t]);
    float denom = 0.f, p[17];
#pragma unroll
    for (int t = 0; t < 17; t++) { p[t] = __expf(s[t] - m); denom += p[t]; }
    const float inv = 1.0f / denom;

    float a[8] = {};
#pragma unroll
    for (int t = 0; t < 17; t++) {
        const int j = i + 2 * t - 16;
        const int jc = (j >= 0 && j < 2048) ? j : i;   // p[t]==0 when invalid
        bf16x8 vv = *(const bf16x8*)(vb + (size_t)jc * 64 + ld);
#pragma unroll
        for (int e = 0; e < 8; e++) a[e] = fmaf(p[t], (float)vv[e], a[e]);
    }

    const int b = bh >> 4, h = bh & 15;
    bf16x8 o;
#pragma unroll
    for (int e = 0; e < 8; e++) o[e] = (__bf16)(a[e] * inv);
    *(bf16x8*)(ao + ((size_t)(b * 2048 + i)) * 1024 + h * 64 + ld) = o;
}

extern "C" void kernel_launch(void* const* d_in, const int* in_sizes, int n_in,
                              void* d_out, int out_size, void* d_ws, size_t ws_size,
                              hipStream_t stream)
{
    const float* x     = (const float*)d_in[0];  // [2,2048,1024]
    const float* w_qkv = (const float*)d_in[1];  // [3072,1024]
    const float* b_qkv = (const float*)d_in[2];  // [3072]
    const float* w_out = (const float*)d_in[3];  // [1024,1024]
    const float* b_out = (const float*)d_in[4];  // [1024]
    float* out = (float*)d_out;                  // [2,2048,1024]

    const int Dn = 1024;
    const int M  = 4096;
    const int nx = 4194304, nwq = 3145728, nwo = 1048576;

    char* p = (char*)d_ws;
    __bf16* q   = (__bf16*)p;  p += (size_t)nx * 2;   // [2,16,2048,64]
    __bf16* kk  = (__bf16*)p;  p += (size_t)nx * 2;
    __bf16* vv  = (__bf16*)p;  p += (size_t)nx * 2;
    __bf16* xh  = (__bf16*)p;  p += (size_t)nx * 2;   // aliased to ao after gemm_qkv
    __bf16* wqh = (__bf16*)p;  p += (size_t)nwq * 2;
    __bf16* woh = (__bf16*)p;  p += (size_t)nwo * 2;
    __bf16* wol = (__bf16*)p;  p += (size_t)nwo * 2;
    __bf16* ao  = xh;

    // 0) x, w_qkv -> bf16 cast; w_out -> hi/lo bf16 split (in-dim permuted)
    {
        dim3 grid(nx / 8 / 256, 3);
        hipLaunchKernelGGL(split_mat, grid, dim3(256), 0, stream,
                           x, xh, (__bf16*)nullptr, nx,
                           w_qkv, wqh, (__bf16*)nullptr, nwq,
                           w_out, woh, wol, nwo);
    }
    // 1) qkv projection + fused qk-norm -> q,k,v bf16 head layout
    {
        dim3 grid(3 * Dn / 128, M / TM);   // 24 x 32 = 768 blocks
        hipLaunchKernelGGL(gemm_qkv, grid, dim3(256), 0, stream,
                           xh, wqh, b_qkv, q, kk, vv, M, 3 * Dn, Dn);
    }
    // 2) sparse dilated attention -> ao bf16 [B,N,D]  (8192 waves)
    hipLaunchKernelGGL(attn_sparse, dim3(2048), dim3(256), 0, stream,
                       q, kk, vv, ao);
    // 3) output projection (2-term) -> fp32 out
    {
        dim3 grid(Dn / 64, M / TM);        // 16 x 32 = 512 blocks
        hipLaunchKernelGGL(gemm_out, grid, dim3(256), 0, stream,
                           ao, woh, wol, b_out, out, M, Dn, Dn);
    }
}

// Round 14
// 160.549 us; speedup vs baseline: 1.0640x; 1.0176x over previous
//
#include <hip/hip_runtime.h>
#include <hip/hip_bf16.h>
#include <math.h>

typedef __bf16 bf16x8 __attribute__((ext_vector_type(8)));
typedef __bf16 bf16x4 __attribute__((ext_vector_type(4)));
typedef float f32x4 __attribute__((ext_vector_type(4)));

#define TM 128
#define BK 128  // K-tile = 2 x 64-col half-tiles, each in the round-1-proven layout

// ---------------------------------------------------------------------------
// Head-dim permutation: q/k/v/ao store dim d at position p = 4*(d&15)+(d>>4)
// (within each 64-dim head block). Attention is dim-order-invariant, so only
// w_out's input-dim columns must be permuted to match (done in split_mat).
// ---------------------------------------------------------------------------

__device__ inline void async16(const void* g, void* l) {
    __builtin_amdgcn_global_load_lds(
        (const __attribute__((address_space(1))) unsigned int*)g,
        (__attribute__((address_space(3))) unsigned int*)l, 16, 0, 0);
}

// Stage a R x 64 bf16 tile with XOR chunk swizzle: LDS chunk (r,c) holds global
// chunk (r, c^(r&7)). ROUND-1 LAYOUT: measured SQ_LDS_BANK_CONFLICT == 0.
__device__ inline void stage_sw(__bf16* S, const __bf16* G, int row0, int K, int k0,
                                int tid, int nchunks) {
#pragma unroll
    for (int ci = tid; ci < nchunks; ci += 256) {
        const int r  = ci >> 3;
        const int c  = ci & 7;
        const int cg = c ^ (r & 7);
        const char* g = (const char*)G + ((size_t)(row0 + r) * K + k0 + cg * 8) * 2;
        async16(g, (char*)S + ci * 16);
    }
}

// Swizzled fragment read: global chunk (r, cfrag) lives at LDS chunk cfrag^(r&7).
__device__ inline bf16x8 frag_sw(const __bf16* S, int r, int cfrag) {
    const int c = cfrag ^ (r & 7);
    return *(const bf16x8*)(S + r * 64 + c * 8);
}

// fp32 -> bf16 hi (+ optional lo). blockIdx.y selects {x, w_qkv, w_out}.
// w_out path (y==2) additionally permutes input-dim columns within each
// 64-block to match the q/k/v/ao head-dim permutation.
__global__ __launch_bounds__(256) void split_mat(
    const float* __restrict__ s0, __bf16* __restrict__ h0, __bf16* __restrict__ l0, int n0,
    const float* __restrict__ s1, __bf16* __restrict__ h1, __bf16* __restrict__ l1, int n1,
    const float* __restrict__ s2, __bf16* __restrict__ h2, __bf16* __restrict__ l2, int n2)
{
    const float* s; __bf16* h; __bf16* l; int n;
    if (blockIdx.y == 0)      { s = s0; h = h0; l = l0; n = n0; }
    else if (blockIdx.y == 1) { s = s1; h = h1; l = l1; n = n1; }
    else                      { s = s2; h = h2; l = l2; n = n2; }
    const int base = (blockIdx.x * 256 + threadIdx.x) * 8;
    if (base >= n) return;

    float buf[8];
    if (blockIdx.y == 2) {
        // permuted gather: position p holds source d(p) = 16*(p&3) + (p>>2)
#pragma unroll
        for (int m = 0; m < 8; m++) {
            const int p   = base + m;
            const int src = (p & ~63) + (((p & 63) >> 2) + 16 * (p & 3));
            buf[m] = s[src];
        }
    } else {
        float4 a = ((const float4*)(s + base))[0];
        float4 b = ((const float4*)(s + base))[1];
        buf[0] = a.x; buf[1] = a.y; buf[2] = a.z; buf[3] = a.w;
        buf[4] = b.x; buf[5] = b.y; buf[6] = b.z; buf[7] = b.w;
    }

    bf16x8 hv, lv;
#pragma unroll
    for (int j = 0; j < 8; j++) {
        __bf16 hb = (__bf16)buf[j];
        hv[j] = hb;
        lv[j] = (__bf16)(buf[j] - (float)hb);
    }
    *(bf16x8*)(h + base) = hv;
    if (l) *(bf16x8*)(l + base) = lv;
}

// QKV projection: C = A*W^T + bias (bf16 MFMA), fused QK-norm, permuted
// scatter into [B,H,N,64]. TN=128, grid 768. BK=128 single-buffer (8 K-steps)
// as two 64-col half-buffers (0-conflict layout; measured 42.8us, conflicts 0).
__global__ __launch_bounds__(256) void gemm_qkv(
    const __bf16* __restrict__ A, const __bf16* __restrict__ W,
    const float* __restrict__ bias,
    __bf16* __restrict__ q, __bf16* __restrict__ k, __bf16* __restrict__ v,
    int M, int N, int K)
{
    __shared__ __bf16 sA[2][TM * 64];
    __shared__ __bf16 sW[2][TM * 64];

    const int tid  = threadIdx.x;
    const int lane = tid & 63;
    const int wave = tid >> 6;
    const int bm = blockIdx.y * TM;
    const int bn = blockIdx.x * 128;
    const int wm = (wave >> 1) * 64;
    const int wn = (wave & 1) * 64;
    const int frow = lane & 15;

    f32x4 acc[4][4] = {};

    for (int k0 = 0; k0 < K; k0 += BK) {
        stage_sw(sA[0], A, bm, K, k0,      tid, TM * 8);
        stage_sw(sA[1], A, bm, K, k0 + 64, tid, TM * 8);
        stage_sw(sW[0], W, bn, K, k0,      tid, TM * 8);
        stage_sw(sW[1], W, bn, K, k0 + 64, tid, TM * 8);
        __syncthreads();

#pragma unroll
        for (int half = 0; half < 4; half++) {
            const __bf16* bA = sA[half >> 1];     // compile-time per half
            const __bf16* bW = sW[half >> 1];
            const int cf = (half & 1) * 4 + (lane >> 4);
            bf16x8 aF[4], bF[4];
#pragma unroll
            for (int t = 0; t < 4; t++) {
                aF[t] = frag_sw(bA, wm + t * 16 + frow, cf);
                bF[t] = frag_sw(bW, wn + t * 16 + frow, cf);
            }
#pragma unroll
            for (int i = 0; i < 4; i++)
#pragma unroll
                for (int j = 0; j < 4; j++)
                    acc[i][j] = __builtin_amdgcn_mfma_f32_16x16x32_bf16(aF[i], bF[j], acc[i][j], 0, 0, 0);
        }
        __syncthreads();
    }

    // wave's 64-col window = exactly one (tensor t, head h)
    const int col0 = bn + wn;
    const int t  = col0 >> 10;            // 0=q 1=k 2=v
    const int h  = (col0 & 1023) >> 6;

    float bv[4];
#pragma unroll
    for (int j = 0; j < 4; j++) bv[j] = bias[col0 + j * 16 + (lane & 15)];

    // fused QK-norm: per output row, 1/(||row||+eps)
    float inv_n[4][4];
    if (t < 2) {
#pragma unroll
        for (int i = 0; i < 4; i++)
#pragma unroll
            for (int r = 0; r < 4; r++) {
                float ss = 0.f;
#pragma unroll
                for (int j = 0; j < 4; j++) {
                    float val = acc[i][j][r] + bv[j];
                    ss = fmaf(val, val, ss);
                }
                ss += __shfl_xor(ss, 1);
                ss += __shfl_xor(ss, 2);
                ss += __shfl_xor(ss, 4);
                ss += __shfl_xor(ss, 8);
                inv_n[i][r] = 1.0f / (sqrtf(ss) + 1e-6f);
            }
    }

    // Permuted store: lane c's four j-values (dims j*16+c) are contiguous at
    // positions 4c..4c+3 -> one bf16x4 per (i,r). Wave store = 4 x 128B runs.
    __bf16* dstbase = (t == 0) ? q : (t == 1) ? k : v;
    const int c4 = (lane & 15) * 4;
#pragma unroll
    for (int i = 0; i < 4; i++) {
        const int gmBase = bm + wm + i * 16 + (lane >> 4) * 4;
#pragma unroll
        for (int r = 0; r < 4; r++) {
            const int gm = gmBase + r;
            bf16x4 ov;
#pragma unroll
            for (int j = 0; j < 4; j++) {
                float val = acc[i][j][r] + bv[j];
                if (t < 2) val *= inv_n[i][r];
                ov[j] = (__bf16)val;
            }
            const int b  = gm >> 11;
            const int ii = gm & 2047;
            *(bf16x4*)(dstbase + (((size_t)(b * 16 + h) * 2048) + ii) * 64 + c4) = ov;
        }
    }
}

// Out projection: C = A(Wh+Wl)^T + bias, A bf16 (2-term), fp32 out.
// TM=128, TN=64 -> 512 blocks. Wave owns 64x32. BK=128 as two 64-col
// half-buffers (0-conflict layout). LDS 64KB (32+16+16) -> 2 blocks/CU.
__global__ __launch_bounds__(256) void gemm_out(
    const __bf16* __restrict__ A,
    const __bf16* __restrict__ Wh, const __bf16* __restrict__ Wl,
    const float* __restrict__ bias, float* __restrict__ C,
    int M, int N, int K)
{
    __shared__ __bf16 sA[2][TM * 64];
    __shared__ __bf16 sWh[2][64 * 64];
    __shared__ __bf16 sWl[2][64 * 64];

    const int tid  = threadIdx.x;
    const int lane = tid & 63;
    const int wave = tid >> 6;
    const int bm = blockIdx.y * TM;
    const int bn = blockIdx.x * 64;
    const int wm = (wave >> 1) * 64;
    const int wn = (wave & 1) * 32;
    const int frow = lane & 15;

    f32x4 acc[4][2] = {};

    for (int k0 = 0; k0 < K; k0 += BK) {
        stage_sw(sA[0],  A,  bm, K, k0,      tid, TM * 8);
        stage_sw(sA[1],  A,  bm, K, k0 + 64, tid, TM * 8);
        stage_sw(sWh[0], Wh, bn, K, k0,      tid, 64 * 8);
        stage_sw(sWh[1], Wh, bn, K, k0 + 64, tid, 64 * 8);
        stage_sw(sWl[0], Wl, bn, K, k0,      tid, 64 * 8);
        stage_sw(sWl[1], Wl, bn, K, k0 + 64, tid, 64 * 8);
        __syncthreads();

#pragma unroll
        for (int half = 0; half < 4; half++) {
            const __bf16* bA  = sA[half >> 1];
            const __bf16* bWh = sWh[half >> 1];
            const __bf16* bWl = sWl[half >> 1];
            const int cf = (half & 1) * 4 + (lane >> 4);
            bf16x8 aH[4], bH[2], bL[2];
#pragma unroll
            for (int t = 0; t < 4; t++)
                aH[t] = frag_sw(bA, wm + t * 16 + frow, cf);
#pragma unroll
            for (int t = 0; t < 2; t++) {
                bH[t] = frag_sw(bWh, wn + t * 16 + frow, cf);
                bL[t] = frag_sw(bWl, wn + t * 16 + frow, cf);
            }
#pragma unroll
            for (int i = 0; i < 4; i++)
#pragma unroll
                for (int j = 0; j < 2; j++) {
                    acc[i][j] = __builtin_amdgcn_mfma_f32_16x16x32_bf16(aH[i], bH[j], acc[i][j], 0, 0, 0);
                    acc[i][j] = __builtin_amdgcn_mfma_f32_16x16x32_bf16(aH[i], bL[j], acc[i][j], 0, 0, 0);
                }
        }
        __syncthreads();
    }

#pragma unroll
    for (int i = 0; i < 4; i++) {
        const int gmBase = bm + wm + i * 16 + (lane >> 4) * 4;
#pragma unroll
        for (int j = 0; j < 2; j++) {
            const int gn = bn + wn + j * 16 + (lane & 15);
            const float bvj = bias[gn];
#pragma unroll
            for (int r = 0; r < 4; r++)
                C[(size_t)(gmBase + r) * N + gn] = acc[i][j][r] + bvj;
        }
    }
}

// Dilated attention: 8 rows per wave; lane group g=lane>>3 owns row i0+g,
// lane&7 owns 8 head-dims (bf16x8, 16B loads). q,k,v: [B,H,N,64] bf16.
// T1 XCD swizzle (NEW this round): dispatch round-robins blocks across the
// 8 XCDs; the dilated gather re-reads each K/V row 17x, and consecutive
// logical blocks (same (b,h), adjacent rows) share that window. Remap so
// each XCD owns 256 consecutive logical blocks = 4 (b,h) = 2MB K+V working
// set < 4MiB per-XCD L2 -> the 17x reuse becomes L2-resident.
__global__ __launch_bounds__(256) void attn_sparse(
    const __bf16* __restrict__ q, const __bf16* __restrict__ k,
    const __bf16* __restrict__ v, __bf16* __restrict__ ao /*[B,N,D] bf16*/)
{
    const int bid  = (int)blockIdx.x;
    const int swz  = (bid & 7) * 256 + (bid >> 3);   // 2048 blocks, %8==0
    const int wid  = swz * 4 + (threadIdx.x >> 6);
    const int lane = threadIdx.x & 63;
    const int g    = lane >> 3;          // row group 0..7
    const int ld   = (lane & 7) * 8;     // dim offset (8 dims per lane)

    const int bh = wid >> 8;             // 256 wave-tasks per (b,h) = 2048/8
    const int i  = (wid & 255) * 8 + g;  // this lane-group's row

    const __bf16* qb = q + (size_t)bh * 2048 * 64;
    const __bf16* kb = k + (size_t)bh * 2048 * 64;
    const __bf16* vb = v + (size_t)bh * 2048 * 64;

    bf16x8 qv = *(const bf16x8*)(qb + (size_t)i * 64 + ld);
    float qf[8];
#pragma unroll
    for (int e = 0; e < 8; e++) qf[e] = (float)qv[e];

    float s[17];
#pragma unroll
    for (int t = 0; t < 17; t++) {
        const int j = i + 2 * t - 16;
        const bool valid = (j >= 0) && (j < 2048);
        const int jc = valid ? j : i;
        bf16x8 kv = *(const bf16x8*)(kb + (size_t)jc * 64 + ld);
        float prod = qf[0] * (float)kv[0];
#pragma unroll
        for (int e = 1; e < 8; e++) prod = fmaf(qf[e], (float)kv[e], prod);
        prod += __shfl_xor(prod, 1);
        prod += __shfl_xor(prod, 2);
        prod += __shfl_xor(prod, 4);
        s[t] = valid ? prod : -INFINITY;
    }

    float m = s[0];
#pragma unroll
    for (int t = 1; t < 17; t++) m = fmaxf(m, s[t]);
    float denom = 0.f, p[17];
#pragma unroll
    for (int t = 0; t < 17; t++) { p[t] = __expf(s[t] - m); denom += p[t]; }
    const float inv = 1.0f / denom;

    float a[8] = {};
#pragma unroll
    for (int t = 0; t < 17; t++) {
        const int j = i + 2 * t - 16;
        const int jc = (j >= 0 && j < 2048) ? j : i;   // p[t]==0 when invalid
        bf16x8 vv = *(const bf16x8*)(vb + (size_t)jc * 64 + ld);
#pragma unroll
        for (int e = 0; e < 8; e++) a[e] = fmaf(p[t], (float)vv[e], a[e]);
    }

    const int b = bh >> 4, h = bh & 15;
    bf16x8 o;
#pragma unroll
    for (int e = 0; e < 8; e++) o[e] = (__bf16)(a[e] * inv);
    *(bf16x8*)(ao + ((size_t)(b * 2048 + i)) * 1024 + h * 64 + ld) = o;
}

extern "C" void kernel_launch(void* const* d_in, const int* in_sizes, int n_in,
                              void* d_out, int out_size, void* d_ws, size_t ws_size,
                              hipStream_t stream)
{
    const float* x     = (const float*)d_in[0];  // [2,2048,1024]
    const float* w_qkv = (const float*)d_in[1];  // [3072,1024]
    const float* b_qkv = (const float*)d_in[2];  // [3072]
    const float* w_out = (const float*)d_in[3];  // [1024,1024]
    const float* b_out = (const float*)d_in[4];  // [1024]
    float* out = (float*)d_out;                  // [2,2048,1024]

    const int Dn = 1024;
    const int M  = 4096;
    const int nx = 4194304, nwq = 3145728, nwo = 1048576;

    char* p = (char*)d_ws;
    __bf16* q   = (__bf16*)p;  p += (size_t)nx * 2;   // [2,16,2048,64]
    __bf16* kk  = (__bf16*)p;  p += (size_t)nx * 2;
    __bf16* vv  = (__bf16*)p;  p += (size_t)nx * 2;
    __bf16* xh  = (__bf16*)p;  p += (size_t)nx * 2;   // aliased to ao after gemm_qkv
    __bf16* wqh = (__bf16*)p;  p += (size_t)nwq * 2;
    __bf16* woh = (__bf16*)p;  p += (size_t)nwo * 2;
    __bf16* wol = (__bf16*)p;  p += (size_t)nwo * 2;
    __bf16* ao  = xh;

    // 0) x, w_qkv -> bf16 cast; w_out -> hi/lo bf16 split (in-dim permuted)
    {
        dim3 grid(nx / 8 / 256, 3);
        hipLaunchKernelGGL(split_mat, grid, dim3(256), 0, stream,
                           x, xh, (__bf16*)nullptr, nx,
                           w_qkv, wqh, (__bf16*)nullptr, nwq,
                           w_out, woh, wol, nwo);
    }
    // 1) qkv projection + fused qk-norm -> q,k,v bf16 head layout
    {
        dim3 grid(3 * Dn / 128, M / TM);   // 24 x 32 = 768 blocks
        hipLaunchKernelGGL(gemm_qkv, grid, dim3(256), 0, stream,
                           xh, wqh, b_qkv, q, kk, vv, M, 3 * Dn, Dn);
    }
    // 2) sparse dilated attention -> ao bf16 [B,N,D]  (8192 waves, XCD-swz)
    hipLaunchKernelGGL(attn_sparse, dim3(2048), dim3(256), 0, stream,
                       q, kk, vv, ao);
    // 3) output projection (2-term) -> fp32 out
    {
        dim3 grid(Dn / 64, M / TM);        // 16 x 32 = 512 blocks
        hipLaunchKernelGGL(gemm_out, grid, dim3(256), 0, stream,
                           ao, woh, wol, b_out, out, M, Dn, Dn);
    }
}